// Round 1
// baseline (411.171 us; speedup 1.0000x reference)
//
#include <hip/hip_runtime.h>
#include <stdint.h>

#define QLEN 1024
#define KLEN 2048
#define BSZ  4
#define NH   16
#define HD   64
#define EMB  1024
#define PREVL 1024

typedef __attribute__((ext_vector_type(4))) float f32x4;
typedef __attribute__((ext_vector_type(8))) short bf16x8;

__device__ __forceinline__ unsigned short f2bf(float f){
  unsigned u = __float_as_uint(f);
  u += 0x7fffu + ((u >> 16) & 1u);
  return (unsigned short)(u >> 16);
}

__device__ __forceinline__ void gload_lds16(const void* g, void* l){
  __builtin_amdgcn_global_load_lds((const __attribute__((address_space(1))) void*)g,
                                   (__attribute__((address_space(3))) void*)l, 16, 0, 0);
}

// ---------------- W transpose: f32 [k][n] -> bf16 [n][k] ----------------
__global__ void txl_transpose_w(const float* __restrict__ in, unsigned short* __restrict__ out){
  __shared__ float tile[32][33];
  int tx = threadIdx.x, ty = threadIdx.y;
  int k0 = blockIdx.y * 32, n0 = blockIdx.x * 32;
  #pragma unroll
  for (int j = 0; j < 32; j += 8)
    tile[ty + j][tx] = in[(size_t)(k0 + ty + j) * EMB + n0 + tx];
  __syncthreads();
  #pragma unroll
  for (int j = 0; j < 32; j += 8)
    out[(size_t)(n0 + ty + j) * EMB + k0 + tx] = f2bf(tile[tx][ty + j]);
}

// ---------------- GEMM: C[M][1024] = A[M][1024] @ Wt^T (+bias) ----------------
// Wt is bf16 [n][k]. MODE: 0=Q (writes Qu,Qv), 1=K, 2=V(transposed out), 3=R, 4=O(f32 out)
template<int MODE>
__global__ __launch_bounds__(256)
void txl_gemm(const void* __restrict__ Ag, const unsigned short* __restrict__ Wt,
              const float* __restrict__ bias, const float* __restrict__ Ub,
              const float* __restrict__ Vb, void* __restrict__ out0, void* __restrict__ out1){
  const int tid = threadIdx.x;
  const int lane = tid & 63, wave = tid >> 6;
  const int lr = lane & 15, lg = lane >> 4;
  const int wm = wave >> 1, wn = wave & 1;
  const int m0 = blockIdx.y * 128, n0 = blockIdx.x * 128;
  __shared__ unsigned short At[128 * 64];
  __shared__ unsigned short Bt[128 * 64];
  f32x4 acc[4][4] = {};

  for (int kt = 0; kt < EMB / 64; ++kt){
    const int k0 = kt * 64;
    __syncthreads();
    // ---- stage A tile [128][64] ----
    if constexpr (MODE == 4){
      const unsigned short* A = (const unsigned short*)Ag;
      #pragma unroll
      for (int j = 0; j < 4; ++j){
        int row = j * 32 + (tid >> 3);
        int g = (tid & 7) ^ (row & 7);
        gload_lds16(A + (size_t)(m0 + row) * EMB + k0 + g * 8, &At[j * 2048 + wave * 512]);
      }
    } else {
      const float* A = (const float*)Ag;
      int row = tid >> 1, half = tid & 1;
      const float* srow = A + (size_t)(m0 + row) * EMB + k0 + half * 32;
      #pragma unroll
      for (int c = 0; c < 4; ++c){
        bf16x8 pk;
        #pragma unroll
        for (int u = 0; u < 8; ++u) pk[u] = (short)f2bf(srow[c * 8 + u]);
        int g = half * 4 + c;
        int cl = g ^ (row & 7);
        *(bf16x8*)&At[row * 64 + cl * 8] = pk;
      }
    }
    // ---- stage B tile [128][64] from Wt rows n0..n0+127 ----
    #pragma unroll
    for (int j = 0; j < 4; ++j){
      int row = j * 32 + (tid >> 3);
      int g = (tid & 7) ^ (row & 7);
      gload_lds16(Wt + (size_t)(n0 + row) * EMB + k0 + g * 8, &Bt[j * 2048 + wave * 512]);
    }
    __syncthreads();
    #pragma unroll
    for (int ks = 0; ks < 2; ++ks){
      bf16x8 af[4], bfr[4];
      #pragma unroll
      for (int mb = 0; mb < 4; ++mb){
        int row = wm * 64 + mb * 16 + lr;
        af[mb] = *(const bf16x8*)&At[row * 64 + ((lg + 4 * ks) ^ (row & 7)) * 8];
      }
      #pragma unroll
      for (int nb = 0; nb < 4; ++nb){
        int row = wn * 64 + nb * 16 + lr;
        bfr[nb] = *(const bf16x8*)&Bt[row * 64 + ((lg + 4 * ks) ^ (row & 7)) * 8];
      }
      #pragma unroll
      for (int mb = 0; mb < 4; ++mb)
        #pragma unroll
        for (int nb = 0; nb < 4; ++nb)
          acc[mb][nb] = __builtin_amdgcn_mfma_f32_16x16x32_bf16(af[mb], bfr[nb], acc[mb][nb], 0, 0, 0);
    }
  }
  // ---- epilogue ----
  #pragma unroll
  for (int mb = 0; mb < 4; ++mb){
    #pragma unroll
    for (int nb = 0; nb < 4; ++nb){
      #pragma unroll
      for (int i = 0; i < 4; ++i){
        int m = m0 + wm * 64 + mb * 16 + 4 * lg + i;
        int n = n0 + wn * 64 + nb * 16 + lr;
        float v = acc[mb][nb][i];
        if constexpr (MODE == 0){
          int q = m >> 2, b = m & 3, h = n >> 6, d = n & 63;
          float base = v + bias[n];
          size_t idx = ((((size_t)b * NH + h) * QLEN) + q) * HD + d;
          ((unsigned short*)out0)[idx] = f2bf(base + Ub[(h << 6) + d]);
          ((unsigned short*)out1)[idx] = f2bf(base + Vb[(h << 6) + d]);
        } else if constexpr (MODE == 1){
          int kp = m >> 2, b = m & 3, h = n >> 6, d = n & 63;
          ((unsigned short*)out0)[((((size_t)b * NH + h) * KLEN) + kp) * HD + d] = f2bf(v + bias[n]);
        } else if constexpr (MODE == 2){
          int kp = m >> 2, b = m & 3, h = n >> 6, d = n & 63;
          ((unsigned short*)out0)[((((size_t)b * NH + h) * HD) + d) * KLEN + kp] = f2bf(v + bias[n]);
        } else if constexpr (MODE == 3){
          int h = n >> 6, d = n & 63;
          ((unsigned short*)out0)[((size_t)h * KLEN + m) * HD + d] = f2bf(v);
        } else {
          ((float*)out0)[(size_t)m * EMB + n] = v + bias[n];
        }
      }
    }
  }
}

// ---------------- fused attention ----------------
// grid (16 q-tiles, 16 heads, 4 batch), 256 threads = 4 waves x 16 q-rows
__global__ __launch_bounds__(256)
void txl_attn(const unsigned short* __restrict__ Qu, const unsigned short* __restrict__ Qv,
              const unsigned short* __restrict__ Kb, const unsigned short* __restrict__ Vt,
              const unsigned short* __restrict__ Rb, unsigned short* __restrict__ alpha){
  const int tid = threadIdx.x, lane = tid & 63, wave = tid >> 6;
  const int lr = lane & 15, lg = lane >> 4;
  const int qt = blockIdx.x, h = blockIdx.y, b = blockIdx.z;
  const int q0 = qt * 64;
  const int myq0 = q0 + 16 * wave;

  __shared__ unsigned short sm_qu[64 * 64];
  __shared__ unsigned short sm_qv[64 * 64];
  __shared__ unsigned short sm_k[64 * 64];
  __shared__ unsigned short sm_v[64 * 64];
  __shared__ unsigned short sm_r[128 * 64];
  __shared__ float sm_t[4][16 * 80];
  __shared__ unsigned short sm_p[4][16 * 64];

  const unsigned short* quB = Qu + (((size_t)b * NH + h) * QLEN) * HD;
  const unsigned short* qvB = Qv + (((size_t)b * NH + h) * QLEN) * HD;
  const unsigned short* kB  = Kb + (((size_t)b * NH + h) * KLEN) * HD;
  const unsigned short* vB  = Vt + (((size_t)b * NH + h) * HD) * KLEN;
  const unsigned short* rB  = Rb + ((size_t)h * KLEN) * HD;

  // stage Q tiles (async; drained at first __syncthreads)
  #pragma unroll
  for (int j = 0; j < 2; ++j){
    int row = j * 32 + (tid >> 3);
    int g = (tid & 7) ^ (row & 7);
    gload_lds16(quB + (size_t)(q0 + row) * HD + g * 8, &sm_qu[j * 2048 + wave * 512]);
    gload_lds16(qvB + (size_t)(q0 + row) * HD + g * 8, &sm_qv[j * 2048 + wave * 512]);
  }

  f32x4 o[4] = {};
  float mx[4], ls[4];
  #pragma unroll
  for (int i = 0; i < 4; ++i){ mx[i] = -3e38f; ls[i] = 0.f; }

  int nk = qt + 17; if (nk > KLEN / 64) nk = KLEN / 64;

  for (int kt = 0; kt < nk; ++kt){
    const int k0 = kt * 64;
    const int rbase = k0 + (QLEN - 64) - q0;   // shared R-band origin
    __syncthreads();
    // stage K, V tiles
    #pragma unroll
    for (int j = 0; j < 2; ++j){
      int row = j * 32 + (tid >> 3);
      int g = (tid & 7) ^ (row & 7);
      gload_lds16(kB + (size_t)(k0 + row) * HD + g * 8, &sm_k[j * 2048 + wave * 512]);
      gload_lds16(vB + (size_t)row * KLEN + k0 + g * 8, &sm_v[j * 2048 + wave * 512]);
    }
    // stage R band (128 rows, clamped)
    #pragma unroll
    for (int j = 0; j < 4; ++j){
      int row = j * 32 + (tid >> 3);
      int g = (tid & 7) ^ (row & 7);
      int r = rbase + row; if (r < 0) r = 0; if (r > KLEN - 1) r = KLEN - 1;
      gload_lds16(rB + (size_t)r * HD + g * 8, &sm_r[j * 2048 + wave * 512]);
    }
    __syncthreads();

    // content scores S_c[16q][64k]
    f32x4 sc[4] = {};
    #pragma unroll
    for (int ks = 0; ks < 2; ++ks){
      int qrow = 16 * wave + lr;
      bf16x8 a = *(const bf16x8*)&sm_qu[qrow * 64 + ((lg + 4 * ks) ^ (qrow & 7)) * 8];
      #pragma unroll
      for (int nb = 0; nb < 4; ++nb){
        int row = nb * 16 + lr;
        bf16x8 bb = *(const bf16x8*)&sm_k[row * 64 + ((lg + 4 * ks) ^ (row & 7)) * 8];
        sc[nb] = __builtin_amdgcn_mfma_f32_16x16x32_bf16(a, bb, sc[nb], 0, 0, 0);
      }
    }
    // position band T[16q][80r]; wave-local R rows start at 48-16*wave
    f32x4 tt[5] = {};
    const int roff = 48 - 16 * wave;
    #pragma unroll
    for (int ks = 0; ks < 2; ++ks){
      int qrow = 16 * wave + lr;
      bf16x8 a = *(const bf16x8*)&sm_qv[qrow * 64 + ((lg + 4 * ks) ^ (qrow & 7)) * 8];
      #pragma unroll
      for (int rb = 0; rb < 5; ++rb){
        int row = roff + rb * 16 + lr;
        bf16x8 bb = *(const bf16x8*)&sm_r[row * 64 + ((lg + 4 * ks) ^ (row & 7)) * 8];
        tt[rb] = __builtin_amdgcn_mfma_f32_16x16x32_bf16(a, bb, tt[rb], 0, 0, 0);
      }
    }
    float* tw = sm_t[wave];
    #pragma unroll
    for (int rb = 0; rb < 5; ++rb)
      #pragma unroll
      for (int i = 0; i < 4; ++i)
        tw[(4 * lg + i) * 80 + rb * 16 + lr] = tt[rb][i];
    asm volatile("s_waitcnt lgkmcnt(0)" ::: "memory");

    // assemble scores, mask, online softmax, write P (swizzled bf16)
    #pragma unroll
    for (int i = 0; i < 4; ++i){
      int qq = 4 * lg + i;
      int qglob = myq0 + qq;
      float sv[4];
      float rowm = -3e38f;
      #pragma unroll
      for (int nb = 0; nb < 4; ++nb){
        int kk = nb * 16 + lr;
        float tv = tw[qq * 80 + kk + 15 - qq];   // diagonal select: r = k + (QLEN-1) - q
        float s = (sc[nb][i] + tv) * 0.03125f;
        if (k0 + kk > qglob + PREVL) s = -1e30f;
        sv[nb] = s;
        rowm = fmaxf(rowm, s);
      }
      #pragma unroll
      for (int off = 1; off < 16; off <<= 1)
        rowm = fmaxf(rowm, __shfl_xor(rowm, off));
      float mnew = fmaxf(mx[i], rowm);
      float scale = __expf(mx[i] - mnew);
      mx[i] = mnew;
      float rsum = 0.f;
      #pragma unroll
      for (int nb = 0; nb < 4; ++nb){
        float p = __expf(sv[nb] - mnew);
        rsum += p;
        int kk = nb * 16 + lr;
        sm_p[wave][qq * 64 + (((kk >> 3) ^ (qq & 7)) << 3) + (kk & 7)] = f2bf(p);
      }
      #pragma unroll
      for (int off = 1; off < 16; off <<= 1)
        rsum += __shfl_xor(rsum, off);
      ls[i] = ls[i] * scale + rsum;
      #pragma unroll
      for (int db = 0; db < 4; ++db) o[db][i] *= scale;
    }
    asm volatile("s_waitcnt lgkmcnt(0)" ::: "memory");

    // PV: O[16q][64d] += P @ V
    #pragma unroll
    for (int ks = 0; ks < 2; ++ks){
      bf16x8 pa = *(const bf16x8*)&sm_p[wave][lr * 64 + ((lg + 4 * ks) ^ (lr & 7)) * 8];
      #pragma unroll
      for (int db = 0; db < 4; ++db){
        int row = db * 16 + lr;
        bf16x8 bb = *(const bf16x8*)&sm_v[row * 64 + ((lg + 4 * ks) ^ (row & 7)) * 8];
        o[db] = __builtin_amdgcn_mfma_f32_16x16x32_bf16(pa, bb, o[db], 0, 0, 0);
      }
    }
  }

  // epilogue: alpha[q][b][h*64+d] bf16
  #pragma unroll
  for (int i = 0; i < 4; ++i){
    float inv = 1.0f / ls[i];
    int q = myq0 + 4 * lg + i;
    #pragma unroll
    for (int db = 0; db < 4; ++db){
      int e = (h << 6) + db * 16 + lr;
      alpha[((size_t)q * BSZ + b) * EMB + e] = f2bf(o[db][i] * inv);
    }
  }
}

extern "C" void kernel_launch(void* const* d_in, const int* in_sizes, int n_in,
                              void* d_out, int out_size, void* d_ws, size_t ws_size,
                              hipStream_t stream) {
  const float* query = (const float*)d_in[0];
  const float* key   = (const float*)d_in[1];
  const float* value = (const float*)d_in[2];
  const float* pos   = (const float*)d_in[3];
  const float* U     = (const float*)d_in[4];
  const float* V     = (const float*)d_in[5];
  const float* Wq    = (const float*)d_in[6];
  const float* bq    = (const float*)d_in[7];
  const float* Wk    = (const float*)d_in[8];
  const float* bk    = (const float*)d_in[9];
  const float* Wv    = (const float*)d_in[10];
  const float* bv    = (const float*)d_in[11];
  const float* Wp    = (const float*)d_in[12];
  const float* Wo    = (const float*)d_in[13];
  const float* bo    = (const float*)d_in[14];

  char* w = (char*)d_ws;
  const size_t MB = 1u << 20;
  unsigned short* WqT = (unsigned short*)(w + 0 * MB);
  unsigned short* WkT = (unsigned short*)(w + 2 * MB);
  unsigned short* WvT = (unsigned short*)(w + 4 * MB);
  unsigned short* WpT = (unsigned short*)(w + 6 * MB);
  unsigned short* WoT = (unsigned short*)(w + 8 * MB);
  unsigned short* Qu  = (unsigned short*)(w + 10 * MB);
  unsigned short* Qv  = (unsigned short*)(w + 18 * MB);
  unsigned short* Kb  = (unsigned short*)(w + 26 * MB);
  unsigned short* Vt  = (unsigned short*)(w + 42 * MB);
  unsigned short* Rb  = (unsigned short*)(w + 58 * MB);
  unsigned short* alpha = (unsigned short*)(w + 62 * MB);

  dim3 tb(32, 8), tg(32, 32);
  txl_transpose_w<<<tg, tb, 0, stream>>>(Wq, WqT);
  txl_transpose_w<<<tg, tb, 0, stream>>>(Wk, WkT);
  txl_transpose_w<<<tg, tb, 0, stream>>>(Wv, WvT);
  txl_transpose_w<<<tg, tb, 0, stream>>>(Wp, WpT);
  txl_transpose_w<<<tg, tb, 0, stream>>>(Wo, WoT);

  txl_gemm<0><<<dim3(8, 32), 256, 0, stream>>>((const void*)query, WqT, bq, U, V, (void*)Qu, (void*)Qv);
  txl_gemm<1><<<dim3(8, 64), 256, 0, stream>>>((const void*)key,   WkT, bk, nullptr, nullptr, (void*)Kb, nullptr);
  txl_gemm<2><<<dim3(8, 64), 256, 0, stream>>>((const void*)value, WvT, bv, nullptr, nullptr, (void*)Vt, nullptr);
  txl_gemm<3><<<dim3(8, 16), 256, 0, stream>>>((const void*)pos,   WpT, nullptr, nullptr, nullptr, (void*)Rb, nullptr);

  txl_attn<<<dim3(16, 16, 4), 256, 0, stream>>>(Qu, Qv, Kb, Vt, Rb, alpha);

  txl_gemm<4><<<dim3(8, 32), 256, 0, stream>>>((const void*)alpha, WoT, bo, nullptr, nullptr, d_out, nullptr);
}